// Round 1
// baseline (1642.187 us; speedup 1.0000x reference)
//
#include <hip/hip_runtime.h>
#include <hip/hip_bf16.h>
#include <stdint.h>

#define NN 512
#define EMBD 64
#define HID 128

typedef float f32x4 __attribute__((ext_vector_type(4)));
typedef short s16x8 __attribute__((ext_vector_type(8)));

// ---------------- Threefry-2x32 (exact JAX semantics) ----------------
__device__ __forceinline__ uint32_t rotl32(uint32_t v, int s){ return (v << s) | (v >> (32 - s)); }

__device__ __forceinline__ void tf2x32(uint32_t k0, uint32_t k1, uint32_t x0, uint32_t x1,
                                       uint32_t &o0, uint32_t &o1){
  uint32_t k2 = k0 ^ k1 ^ 0x1BD11BDAu;
  x0 += k0; x1 += k1;
  x0+=x1; x1=rotl32(x1,13); x1^=x0;
  x0+=x1; x1=rotl32(x1,15); x1^=x0;
  x0+=x1; x1=rotl32(x1,26); x1^=x0;
  x0+=x1; x1=rotl32(x1, 6); x1^=x0;
  x0 += k1; x1 += k2 + 1u;
  x0+=x1; x1=rotl32(x1,17); x1^=x0;
  x0+=x1; x1=rotl32(x1,29); x1^=x0;
  x0+=x1; x1=rotl32(x1,16); x1^=x0;
  x0+=x1; x1=rotl32(x1,24); x1^=x0;
  x0 += k2; x1 += k0 + 2u;
  x0+=x1; x1=rotl32(x1,13); x1^=x0;
  x0+=x1; x1=rotl32(x1,15); x1^=x0;
  x0+=x1; x1=rotl32(x1,26); x1^=x0;
  x0+=x1; x1=rotl32(x1, 6); x1^=x0;
  x0 += k0; x1 += k1 + 3u;
  x0+=x1; x1=rotl32(x1,17); x1^=x0;
  x0+=x1; x1=rotl32(x1,29); x1^=x0;
  x0+=x1; x1=rotl32(x1,16); x1^=x0;
  x0+=x1; x1=rotl32(x1,24); x1^=x0;
  x0 += k1; x1 += k2 + 4u;
  x0+=x1; x1=rotl32(x1,13); x1^=x0;
  x0+=x1; x1=rotl32(x1,15); x1^=x0;
  x0+=x1; x1=rotl32(x1,26); x1^=x0;
  x0+=x1; x1=rotl32(x1, 6); x1^=x0;
  x0 += k2; x1 += k0 + 5u;
  o0 = x0; o1 = x1;
}

// uniform(key,(n,),0.01,0.1) bit-exact elementwise transform
__device__ __forceinline__ float bits_to_noise(uint32_t bits){
  float u = __builtin_bit_cast(float, (bits >> 9) | 0x3f800000u) - 1.0f;
  const float dlt = 0.1f - 0.01f;             // f32 constant fold, as XLA does
  float v = __fadd_rn(__fmul_rn(u, dlt), 0.01f); // keep mul/add separate (no FMA)
  return fmaxf(0.01f, v);
}

__device__ __forceinline__ short f2bf(float f){
  uint32_t u = __builtin_bit_cast(uint32_t, f);
  u += 0x7fffu + ((u >> 16) & 1u);
  return (short)(u >> 16);
}

__device__ __forceinline__ float fsig(float x){
  return __builtin_amdgcn_rcpf(1.0f + __expf(-x));
}
__device__ __forceinline__ float ftanh(float x){
  float e = __expf(2.0f * x);
  return 1.0f - 2.0f * __builtin_amdgcn_rcpf(e + 1.0f);
}
__device__ __forceinline__ float softplusf(float x){
  return log1pf(expf(x));   // |x| is small here; no overflow concerns
}

// ---------------- K1: input_feat = [emb(tag), A@emb + b] ----------------
__global__ __launch_bounds__(64) void k_feat(const int* __restrict__ tags,
                                             const float* __restrict__ adj,
                                             const float* __restrict__ W_emb,
                                             const float* __restrict__ b_emb,
                                             float* __restrict__ feat){
  int n = blockIdx.x, d = threadIdx.x;
  __shared__ int tg[NN];
  for (int i = d; i < NN; i += 64) tg[i] = tags[i];
  __syncthreads();
  float nf = W_emb[tg[n]*EMBD + d] + b_emb[d];
  float acc = 0.f;
  for (int m = 0; m < NN; ++m){
    float a = adj[n*NN + m];
    if (a > 0.5f) acc += W_emb[tg[m]*EMBD + d];
  }
  feat[n*2*EMBD + d]        = nf;
  feat[n*2*EMBD + EMBD + d] = acc + b_emb[d];
}

// ---------------- K2: greedy noisy random-walk orders ----------------
__global__ __launch_bounds__(256) void k_orders(const float* __restrict__ adj,
                                                int* __restrict__ orders){
  int s = blockIdx.x, tid = threadIdx.x;
  int lane = tid & 63, wid = tid >> 6;
  __shared__ double red_v[2][4];
  __shared__ int    red_i[2][4];
  __shared__ uint32_t ktl[2][2];

  // key_s = threefry(root=(0,42); x=(0,s))   (partitionable foldlike split)
  uint32_t ks0, ks1; tf2x32(0u, 42u, 0u, (uint32_t)s, ks0, ks1);

  int p0 = tid*2, p1 = tid*2 + 1;
  int m0 = (p0 != s), m1 = (p1 != s);
  int cur = s;
  if (tid == 0){
    orders[s*NN] = s;
    uint32_t a, b; tf2x32(ks0, ks1, 0u, 0u, a, b);  // kt for t=0
    ktl[0][0] = a; ktl[0][1] = b;
  }
  __syncthreads();

  for (int t = 0; t < NN-1; ++t){
    const float2 av = *(const float2*)(adj + (size_t)cur*NN + p0);
    uint32_t kt0 = ktl[t&1][0], kt1 = ktl[t&1][1];
    uint32_t a0,b0,a1,b1;
    tf2x32(kt0, kt1, 0u, (uint32_t)p0, a0, b0);
    tf2x32(kt0, kt1, 0u, (uint32_t)p1, a1, b1);
    float n0 = bits_to_noise(a0 ^ b0);
    float n1 = bits_to_noise(a1 ^ b1);
    double v0 = m0 ? (double)av.x + (double)n0 : -1.0;
    double v1 = m1 ? (double)av.y + (double)n1 : -1.0;
    double bv = v0; int bi = p0;
    if (v1 > bv){ bv = v1; bi = p1; }
    #pragma unroll
    for (int off = 1; off < 64; off <<= 1){
      double ov = __shfl_xor(bv, off);
      int    oi = __shfl_xor(bi, off);
      if (ov > bv || (ov == bv && oi < bi)){ bv = ov; bi = oi; }
    }
    if (lane == 0){ red_v[t&1][wid] = bv; red_i[t&1][wid] = bi; }
    if (tid == 0 && t + 1 < NN-1){                     // kt for next step
      uint32_t a, b; tf2x32(ks0, ks1, 0u, (uint32_t)(t+1), a, b);
      ktl[(t+1)&1][0] = a; ktl[(t+1)&1][1] = b;
    }
    __syncthreads();
    bv = red_v[t&1][0]; bi = red_i[t&1][0];
    #pragma unroll
    for (int wq = 1; wq < 4; ++wq){
      double ov = red_v[t&1][wq]; int oi = red_i[t&1][wq];
      if (ov > bv || (ov == bv && oi < bi)){ bv = ov; bi = oi; }
    }
    cur = bi;
    if (bi == p0) m0 = 0;
    if (bi == p1) m1 = 0;
    if (tid == 0) orders[s*NN + t + 1] = bi;
  }
}

// ---------------- K3: IFW[n][g] = feat[n]·W_ih[g] + b_ih[g]+b_hh[g] ----------------
__global__ __launch_bounds__(256) void k_ifw(const float* __restrict__ feat,
                                             const float* __restrict__ W_ih,
                                             const float* __restrict__ b_ih,
                                             const float* __restrict__ b_hh,
                                             float* __restrict__ IFW){
  int n = blockIdx.x, tid = threadIdx.x;
  __shared__ float xs[2*EMBD];
  if (tid < 2*EMBD) xs[tid] = feat[n*2*EMBD + tid];
  __syncthreads();
  for (int g = tid; g < 4*HID; g += 256){
    float acc = b_ih[g] + b_hh[g];
    const float* wr = W_ih + (size_t)g*2*EMBD;
    #pragma unroll 8
    for (int k = 0; k < 2*EMBD; ++k) acc += xs[k] * wr[k];
    IFW[(size_t)n*4*HID + g] = acc;
  }
}

// ---------------- K4: persistent LSTM, W_hh in register MFMA fragments ----------------
__global__ __launch_bounds__(256, 1) void k_lstm(const float* __restrict__ W_hh,
                                                 const float* __restrict__ IFW,
                                                 const int* __restrict__ orders,
                                                 float* __restrict__ embed){
  int wg  = blockIdx.x;            // sequences 16*wg .. 16*wg+15
  int tid = threadIdx.x;
  int w   = tid >> 6;              // wave 0..3 -> d-tiles {2w, 2w+1}
  int l   = tid & 63;
  int l15 = l & 15, l4 = l >> 4;

  __shared__ int ord_s[16*NN];                       // 32 KB
  __shared__ __align__(16) short hbuf[2][16][HID+8]; // 8.7 KB, padded rows

  for (int i = tid; i < 16*NN; i += 256){
    int m = i >> 9, t = i & (NN-1);
    ord_s[i] = orders[(size_t)(16*wg + m)*NN + t];
  }
  for (int i = tid; i < 16*(HID+8); i += 256)
    hbuf[0][i/(HID+8)][i%(HID+8)] = 0;

  // W_hh -> bf16 B-fragments in registers: Bf[q][j][kt], q=gate type i/f/g/o
  s16x8 Bf[4][2][4];
  #pragma unroll
  for (int q = 0; q < 4; ++q)
    #pragma unroll
    for (int j = 0; j < 2; ++j){
      int g = (q*8 + 2*w + j)*16 + l15;
      #pragma unroll
      for (int kt = 0; kt < 4; ++kt){
        int k0 = kt*32 + l4*8;
        const float* src = W_hh + (size_t)g*HID + k0;
        s16x8 v;
        #pragma unroll
        for (int e = 0; e < 8; ++e) v[e] = f2bf(src[e]);
        Bf[q][j][kt] = v;
      }
    }
  __syncthreads();

  float c[4][2]   = {};
  float emb[4][2] = {};

  for (int t = 0; t < NN; ++t){
    int pb = t & 1, wb = 1 - pb;    // t=0 reads buf0 (zeroed)

    // IFW gather for this step (issued early; overlaps MFMA)
    float vIF[4][2][4];
    #pragma unroll
    for (int r = 0; r < 4; ++r){
      int m = l4*4 + r;
      int ord = ord_s[m*NN + t];
      const float* base = IFW + (size_t)ord*4*HID + 2*w*16 + l15;
      #pragma unroll
      for (int q = 0; q < 4; ++q)
        #pragma unroll
        for (int j = 0; j < 2; ++j)
          vIF[q][j][r] = base[q*128 + j*16];
    }

    // A-fragments from LDS (h_{t-1}), row = l15, 8 consecutive k
    s16x8 Af[4];
    #pragma unroll
    for (int kt = 0; kt < 4; ++kt)
      Af[kt] = *(const s16x8*)&hbuf[pb][l15][kt*32 + l4*8];

    f32x4 acc[4][2];
    #pragma unroll
    for (int q = 0; q < 4; ++q)
      #pragma unroll
      for (int j = 0; j < 2; ++j){
        f32x4 a = {0.f, 0.f, 0.f, 0.f};
        #pragma unroll
        for (int kt = 0; kt < 4; ++kt)
          a = __builtin_amdgcn_mfma_f32_16x16x32_bf16(Af[kt], Bf[q][j][kt], a, 0, 0, 0);
        acc[q][j] = a;
      }

    // epilogue: lane-local i/f/g/o (C layout: col=lane&15=gate, row=(l>>4)*4+r=seq)
    #pragma unroll
    for (int r = 0; r < 4; ++r)
      #pragma unroll
      for (int j = 0; j < 2; ++j){
        float gi = acc[0][j][r] + vIF[0][j][r];
        float gf = acc[1][j][r] + vIF[1][j][r];
        float gg = acc[2][j][r] + vIF[2][j][r];
        float go = acc[3][j][r] + vIF[3][j][r];
        float si = fsig(gi), sf = fsig(gf), so = fsig(go);
        float tg = ftanh(gg);
        float cn = sf * c[r][j] + si * tg;
        c[r][j] = cn;
        float h = so * ftanh(cn);
        emb[r][j] += h;
        hbuf[wb][l4*4 + r][(2*w + j)*16 + l15] = f2bf(h);
      }
    __syncthreads();
  }

  #pragma unroll
  for (int r = 0; r < 4; ++r)
    #pragma unroll
    for (int j = 0; j < 2; ++j){
      int m = l4*4 + r, d = (2*w + j)*16 + l15;
      embed[(size_t)(16*wg + m)*HID + d] = emb[r][j] * (1.0f/512.0f);
    }
}

// ---------------- K5: 4 MLP heads -> logits[k][n] ----------------
__global__ __launch_bounds__(128) void k_heads(const float* __restrict__ embed,
                                               const float* __restrict__ W1s,
                                               const float* __restrict__ b1s,
                                               const float* __restrict__ W2s,
                                               const float* __restrict__ b2s,
                                               float* __restrict__ logits){
  int n = blockIdx.x, tid = threadIdx.x;  // tid = hidden unit h
  __shared__ float es[HID];
  __shared__ float part[2];
  es[tid] = embed[(size_t)n*HID + tid];
  __syncthreads();
  for (int k = 0; k < 4; ++k){
    float pre = b1s[k*HID + tid];
    const float* wk = W1s + (size_t)k*HID*HID + tid;
    #pragma unroll 4
    for (int d = 0; d < HID; ++d) pre += es[d] * wk[(size_t)d*HID];
    float v = fmaxf(pre, 0.f) * W2s[k*HID + tid];
    #pragma unroll
    for (int off = 1; off < 64; off <<= 1) v += __shfl_xor(v, off);
    if ((tid & 63) == 0) part[tid >> 6] = v;
    __syncthreads();
    if (tid == 0) logits[k*NN + n] = part[0] + part[1] + b2s[k];
    __syncthreads();
  }
}

// ---------------- K6: BCE loss + softplus-weighted mixture ----------------
__global__ __launch_bounds__(512) void k_final(const float* __restrict__ logits,
                                               const int* __restrict__ label,
                                               const float* __restrict__ var_raw,
                                               float* __restrict__ out){
  int n = threadIdx.x;
  float lab = (float)label[0];
  float sp[4]; float tot = 0.f;
  #pragma unroll
  for (int k = 0; k < 4; ++k){ sp[k] = softplusf(var_raw[k]); tot += sp[k]; }
  float y = 0.f, bce = 0.f;
  #pragma unroll
  for (int k = 0; k < 4; ++k){
    float x = logits[k*NN + n];
    float yk = 1.0f / (1.0f + expf(-x));
    y += (sp[k] / tot) * yk;
    bce += lab * softplusf(-x) + (1.0f - lab) * softplusf(x);
  }
  out[1 + n] = y;
  __shared__ float pr[8];
  #pragma unroll
  for (int off = 1; off < 64; off <<= 1) bce += __shfl_xor(bce, off);
  if ((n & 63) == 0) pr[n >> 6] = bce;
  __syncthreads();
  if (n == 0){
    float ssum = 0.f;
    for (int i = 0; i < 8; ++i) ssum += pr[i];
    out[0] = ssum * (1.0f/512.0f);
  }
}

// ---------------- launcher ----------------
extern "C" void kernel_launch(void* const* d_in, const int* in_sizes, int n_in,
                              void* d_out, int out_size, void* d_ws, size_t ws_size,
                              hipStream_t stream) {
  const int*   node_tags = (const int*)  d_in[0];
  const float* adj       = (const float*)d_in[1];
  const int*   label     = (const int*)  d_in[2];
  const float* W_emb     = (const float*)d_in[3];
  const float* b_emb     = (const float*)d_in[4];
  const float* W_ih      = (const float*)d_in[5];
  const float* W_hh      = (const float*)d_in[6];
  const float* b_ih      = (const float*)d_in[7];
  const float* b_hh      = (const float*)d_in[8];
  const float* W1s       = (const float*)d_in[9];
  const float* b1s       = (const float*)d_in[10];
  const float* W2s       = (const float*)d_in[11];
  const float* b2s       = (const float*)d_in[12];
  const float* var_raw   = (const float*)d_in[13];
  float* out = (float*)d_out;

  float* ws     = (float*)d_ws;
  float* feat   = ws;                      // 512*128        = 65536
  float* IFW    = feat + 65536;            // 512*512        = 262144
  float* embed  = IFW + 262144;            // 512*128        = 65536
  float* logits = embed + 65536;           // 4*512          = 2048
  int*   orders = (int*)(logits + 2048);   // 512*512 int32  = 262144

  k_orders<<<dim3(NN),  dim3(256), 0, stream>>>(adj, orders);
  k_feat  <<<dim3(NN),  dim3(64),  0, stream>>>(node_tags, adj, W_emb, b_emb, feat);
  k_ifw   <<<dim3(NN),  dim3(256), 0, stream>>>(feat, W_ih, b_ih, b_hh, IFW);
  k_lstm  <<<dim3(32),  dim3(256), 0, stream>>>(W_hh, IFW, orders, embed);
  k_heads <<<dim3(NN),  dim3(128), 0, stream>>>(embed, W1s, b1s, W2s, b2s, logits);
  k_final <<<dim3(1),   dim3(512), 0, stream>>>(logits, label, var_raw, out);
}

// Round 2
// 1497.640 us; speedup vs baseline: 1.0965x; 1.0965x over previous
//
#include <hip/hip_runtime.h>
#include <hip/hip_bf16.h>
#include <stdint.h>

#define NN 512
#define EMBD 64
#define HID 128

typedef float f32x4 __attribute__((ext_vector_type(4)));
typedef short s16x8 __attribute__((ext_vector_type(8)));

// ---------------- Threefry-2x32 (exact JAX semantics) ----------------
__device__ __forceinline__ uint32_t rotl32(uint32_t v, int s){ return (v << s) | (v >> (32 - s)); }

__device__ __forceinline__ void tf2x32(uint32_t k0, uint32_t k1, uint32_t x0, uint32_t x1,
                                       uint32_t &o0, uint32_t &o1){
  uint32_t k2 = k0 ^ k1 ^ 0x1BD11BDAu;
  x0 += k0; x1 += k1;
  x0+=x1; x1=rotl32(x1,13); x1^=x0;
  x0+=x1; x1=rotl32(x1,15); x1^=x0;
  x0+=x1; x1=rotl32(x1,26); x1^=x0;
  x0+=x1; x1=rotl32(x1, 6); x1^=x0;
  x0 += k1; x1 += k2 + 1u;
  x0+=x1; x1=rotl32(x1,17); x1^=x0;
  x0+=x1; x1=rotl32(x1,29); x1^=x0;
  x0+=x1; x1=rotl32(x1,16); x1^=x0;
  x0+=x1; x1=rotl32(x1,24); x1^=x0;
  x0 += k2; x1 += k0 + 2u;
  x0+=x1; x1=rotl32(x1,13); x1^=x0;
  x0+=x1; x1=rotl32(x1,15); x1^=x0;
  x0+=x1; x1=rotl32(x1,26); x1^=x0;
  x0+=x1; x1=rotl32(x1, 6); x1^=x0;
  x0 += k0; x1 += k1 + 3u;
  x0+=x1; x1=rotl32(x1,17); x1^=x0;
  x0+=x1; x1=rotl32(x1,29); x1^=x0;
  x0+=x1; x1=rotl32(x1,16); x1^=x0;
  x0+=x1; x1=rotl32(x1,24); x1^=x0;
  x0 += k1; x1 += k2 + 4u;
  x0+=x1; x1=rotl32(x1,13); x1^=x0;
  x0+=x1; x1=rotl32(x1,15); x1^=x0;
  x0+=x1; x1=rotl32(x1,26); x1^=x0;
  x0+=x1; x1=rotl32(x1, 6); x1^=x0;
  x0 += k2; x1 += k0 + 5u;
  o0 = x0; o1 = x1;
}

// uniform(key,(n,),0.01,0.1) bit-exact elementwise transform
__device__ __forceinline__ float bits_to_noise(uint32_t bits){
  float u = __builtin_bit_cast(float, (bits >> 9) | 0x3f800000u) - 1.0f;
  const float dlt = 0.1f - 0.01f;             // f32 constant fold, as XLA does
  float v = __fadd_rn(__fmul_rn(u, dlt), 0.01f); // keep mul/add separate (no FMA)
  return fmaxf(0.01f, v);
}

__device__ __forceinline__ short f2bf(float f){
  uint32_t u = __builtin_bit_cast(uint32_t, f);
  u += 0x7fffu + ((u >> 16) & 1u);
  return (short)(u >> 16);
}

__device__ __forceinline__ float fsig(float x){
  return __builtin_amdgcn_rcpf(1.0f + __expf(-x));
}
__device__ __forceinline__ float ftanh(float x){
  float e = __expf(2.0f * x);
  return 1.0f - 2.0f * __builtin_amdgcn_rcpf(e + 1.0f);
}
__device__ __forceinline__ float softplusf(float x){
  return log1pf(expf(x));
}

// ---------------- K1: input_feat = [emb(tag), A@emb + b] ----------------
__global__ __launch_bounds__(64) void k_feat(const int* __restrict__ tags,
                                             const float* __restrict__ adj,
                                             const float* __restrict__ W_emb,
                                             const float* __restrict__ b_emb,
                                             float* __restrict__ feat){
  int n = blockIdx.x, d = threadIdx.x;
  __shared__ int tg[NN];
  for (int i = d; i < NN; i += 64) tg[i] = tags[i];
  __syncthreads();
  float nf = W_emb[tg[n]*EMBD + d] + b_emb[d];
  float acc = 0.f;
  for (int m = 0; m < NN; ++m){
    float a = adj[n*NN + m];
    if (a > 0.5f) acc += W_emb[tg[m]*EMBD + d];
  }
  feat[n*2*EMBD + d]        = nf;
  feat[n*2*EMBD + EMBD + d] = acc + b_emb[d];
}

// ---------------- K2: greedy noisy random-walk orders (pruned) ----------------
// Winner of step t = argmax over unvisited i of adj[cur,i]+noise_i, noise in
// [0.01,0.1).  Only i with adj_i > M-0.09 (M = max unvisited adj) can win, so
// threefry runs only on that compacted candidate set (avg ~23 vs 512).
// v = f64(adj)+f64(noise) is a multiple of 2^-30 (adj: 2^-23 grid; noise: f32
// with LSB >= 2^-30), so key=((u64)(v*2^30)<<9)|(511-idx) is an exact order
// embedding incl. tie-break (smaller idx wins) -> winner identical to round 1.
__global__ __launch_bounds__(64) void k_orders(const float* __restrict__ adj,
                                               int* __restrict__ orders){
  int s = blockIdx.x, lane = threadIdx.x;
  __shared__ uint32_t kts[2*(NN-1)];   // per-step derived keys
  __shared__ float    ca[NN];          // candidate adj values
  __shared__ int      ci[NN];          // candidate indices

  uint32_t ks0, ks1; tf2x32(0u, 42u, 0u, (uint32_t)s, ks0, ks1);
  for (int t = lane; t < NN-1; t += 64){
    uint32_t a, b; tf2x32(ks0, ks1, 0u, (uint32_t)t, a, b);
    kts[2*t] = a; kts[2*t+1] = b;
  }

  uint32_t vis = 0;                    // 8 index slots per lane: i = lane+64*j
  if ((s & 63) == lane) vis |= 1u << (s >> 6);
  int cur = s;
  if (lane == 0) orders[(size_t)s*NN] = s;
  __syncthreads();

  for (int t = 0; t < NN-1; ++t){
    const float* row = adj + (size_t)cur*NN;
    float a[8];
    #pragma unroll
    for (int j = 0; j < 8; ++j) a[j] = row[lane + 64*j];

    // max over unvisited
    float mx = -1.f;
    #pragma unroll
    for (int j = 0; j < 8; ++j)
      mx = fmaxf(mx, ((vis >> j) & 1) ? -1.f : a[j]);
    #pragma unroll
    for (int off = 1; off < 64; off <<= 1)
      mx = fmaxf(mx, __shfl_xor(mx, off));
    float thresh = mx - 0.0901f;

    // compact candidates into LDS
    int total = 0;
    #pragma unroll
    for (int j = 0; j < 8; ++j){
      bool cand = !((vis >> j) & 1) && (a[j] >= thresh);
      unsigned long long bal = __ballot(cand);
      int pos = total + __popcll(bal & ((1ull << lane) - 1ull));
      if (cand){ ca[pos] = a[j]; ci[pos] = lane + 64*j; }
      total += __popcll(bal);
    }
    __syncthreads();                   // LDS write->read visibility

    // evaluate candidates (threefry only here)
    unsigned long long best = 0;
    uint32_t kt0 = kts[2*t], kt1 = kts[2*t+1];
    for (int b0 = 0; b0 < total; b0 += 64){
      int k = b0 + lane;
      if (k < total){
        int idx = ci[k];
        uint32_t x0, x1;
        tf2x32(kt0, kt1, 0u, (uint32_t)idx, x0, x1);
        float nz = bits_to_noise(x0 ^ x1);
        double v = (double)ca[k] + (double)nz;
        unsigned long long iv = (unsigned long long)(v * 1073741824.0); // *2^30, exact
        unsigned long long key = (iv << 9) | (unsigned long long)(NN-1 - idx);
        best = key > best ? key : best;
      }
    }
    #pragma unroll
    for (int off = 1; off < 64; off <<= 1){
      unsigned long long o = __shfl_xor(best, off);
      best = o > best ? o : best;
    }
    cur = (NN-1) - (int)(best & (unsigned long long)(NN-1));
    if ((cur & 63) == lane) vis |= 1u << (cur >> 6);
    if (lane == 0) orders[(size_t)s*NN + t + 1] = cur;
    __syncthreads();                   // protect ca/ci reuse next step
  }
}

// ---------------- K3: IFW[n][g] = feat[n]·W_ih[g] + b_ih[g]+b_hh[g] ----------------
__global__ __launch_bounds__(256) void k_ifw(const float* __restrict__ feat,
                                             const float* __restrict__ W_ih,
                                             const float* __restrict__ b_ih,
                                             const float* __restrict__ b_hh,
                                             float* __restrict__ IFW){
  int n = blockIdx.x, tid = threadIdx.x;
  __shared__ float xs[2*EMBD];
  if (tid < 2*EMBD) xs[tid] = feat[n*2*EMBD + tid];
  __syncthreads();
  for (int g = tid; g < 4*HID; g += 256){
    float acc = b_ih[g] + b_hh[g];
    const float* wr = W_ih + (size_t)g*2*EMBD;
    #pragma unroll 8
    for (int k = 0; k < 2*EMBD; ++k) acc += xs[k] * wr[k];
    IFW[(size_t)n*4*HID + g] = acc;
  }
}

// ---------------- K4: persistent LSTM, W_hh in register MFMA fragments ----------------
__global__ __launch_bounds__(256, 1) void k_lstm(const float* __restrict__ W_hh,
                                                 const float* __restrict__ IFW,
                                                 const int* __restrict__ orders,
                                                 float* __restrict__ embed){
  int wg  = blockIdx.x;            // sequences 16*wg .. 16*wg+15
  int tid = threadIdx.x;
  int w   = tid >> 6;              // wave 0..3 -> d-tiles {2w, 2w+1}
  int l   = tid & 63;
  int l15 = l & 15, l4 = l >> 4;

  __shared__ int ord_s[16*NN];                       // 32 KB
  __shared__ __align__(16) short hbuf[2][16][HID+8]; // 8.7 KB, padded rows

  for (int i = tid; i < 16*NN; i += 256){
    int m = i >> 9, t = i & (NN-1);
    ord_s[i] = orders[(size_t)(16*wg + m)*NN + t];
  }
  for (int i = tid; i < 16*(HID+8); i += 256)
    hbuf[0][i/(HID+8)][i%(HID+8)] = 0;

  // W_hh -> bf16 B-fragments in registers: Bf[q][j][kt], q=gate type i/f/g/o
  s16x8 Bf[4][2][4];
  #pragma unroll
  for (int q = 0; q < 4; ++q)
    #pragma unroll
    for (int j = 0; j < 2; ++j){
      int g = (q*8 + 2*w + j)*16 + l15;
      #pragma unroll
      for (int kt = 0; kt < 4; ++kt){
        int k0 = kt*32 + l4*8;
        const float* src = W_hh + (size_t)g*HID + k0;
        s16x8 v;
        #pragma unroll
        for (int e = 0; e < 8; ++e) v[e] = f2bf(src[e]);
        Bf[q][j][kt] = v;
      }
    }
  __syncthreads();

  float c[4][2]   = {};
  float emb[4][2] = {};

  for (int t = 0; t < NN; ++t){
    int pb = t & 1, wb = 1 - pb;    // t=0 reads buf0 (zeroed)

    // IFW gather for this step (issued early; overlaps MFMA)
    float vIF[4][2][4];
    #pragma unroll
    for (int r = 0; r < 4; ++r){
      int m = l4*4 + r;
      int ord = ord_s[m*NN + t];
      const float* base = IFW + (size_t)ord*4*HID + 2*w*16 + l15;
      #pragma unroll
      for (int q = 0; q < 4; ++q)
        #pragma unroll
        for (int j = 0; j < 2; ++j)
          vIF[q][j][r] = base[q*128 + j*16];
    }

    // A-fragments from LDS (h_{t-1}), row = l15, 8 consecutive k
    s16x8 Af[4];
    #pragma unroll
    for (int kt = 0; kt < 4; ++kt)
      Af[kt] = *(const s16x8*)&hbuf[pb][l15][kt*32 + l4*8];

    f32x4 acc[4][2];
    #pragma unroll
    for (int q = 0; q < 4; ++q)
      #pragma unroll
      for (int j = 0; j < 2; ++j){
        f32x4 a = {0.f, 0.f, 0.f, 0.f};
        #pragma unroll
        for (int kt = 0; kt < 4; ++kt)
          a = __builtin_amdgcn_mfma_f32_16x16x32_bf16(Af[kt], Bf[q][j][kt], a, 0, 0, 0);
        acc[q][j] = a;
      }

    // epilogue: lane-local i/f/g/o (C layout: col=lane&15=gate, row=(l>>4)*4+r=seq)
    #pragma unroll
    for (int r = 0; r < 4; ++r)
      #pragma unroll
      for (int j = 0; j < 2; ++j){
        float gi = acc[0][j][r] + vIF[0][j][r];
        float gf = acc[1][j][r] + vIF[1][j][r];
        float gg = acc[2][j][r] + vIF[2][j][r];
        float go = acc[3][j][r] + vIF[3][j][r];
        float si = fsig(gi), sf = fsig(gf), so = fsig(go);
        float tg = ftanh(gg);
        float cn = sf * c[r][j] + si * tg;
        c[r][j] = cn;
        float h = so * ftanh(cn);
        emb[r][j] += h;
        hbuf[wb][l4*4 + r][(2*w + j)*16 + l15] = f2bf(h);
      }
    __syncthreads();
  }

  #pragma unroll
  for (int r = 0; r < 4; ++r)
    #pragma unroll
    for (int j = 0; j < 2; ++j){
      int m = l4*4 + r, d = (2*w + j)*16 + l15;
      embed[(size_t)(16*wg + m)*HID + d] = emb[r][j] * (1.0f/512.0f);
    }
}

// ---------------- K5: 4 MLP heads -> logits[k][n] ----------------
__global__ __launch_bounds__(128) void k_heads(const float* __restrict__ embed,
                                               const float* __restrict__ W1s,
                                               const float* __restrict__ b1s,
                                               const float* __restrict__ W2s,
                                               const float* __restrict__ b2s,
                                               float* __restrict__ logits){
  int n = blockIdx.x, tid = threadIdx.x;  // tid = hidden unit h
  __shared__ float es[HID];
  __shared__ float part[2];
  es[tid] = embed[(size_t)n*HID + tid];
  __syncthreads();
  for (int k = 0; k < 4; ++k){
    float pre = b1s[k*HID + tid];
    const float* wk = W1s + (size_t)k*HID*HID + tid;
    #pragma unroll 4
    for (int d = 0; d < HID; ++d) pre += es[d] * wk[(size_t)d*HID];
    float v = fmaxf(pre, 0.f) * W2s[k*HID + tid];
    #pragma unroll
    for (int off = 1; off < 64; off <<= 1) v += __shfl_xor(v, off);
    if ((tid & 63) == 0) part[tid >> 6] = v;
    __syncthreads();
    if (tid == 0) logits[k*NN + n] = part[0] + part[1] + b2s[k];
    __syncthreads();
  }
}

// ---------------- K6: BCE loss + softplus-weighted mixture ----------------
__global__ __launch_bounds__(512) void k_final(const float* __restrict__ logits,
                                               const int* __restrict__ label,
                                               const float* __restrict__ var_raw,
                                               float* __restrict__ out){
  int n = threadIdx.x;
  float lab = (float)label[0];
  float sp[4]; float tot = 0.f;
  #pragma unroll
  for (int k = 0; k < 4; ++k){ sp[k] = softplusf(var_raw[k]); tot += sp[k]; }
  float y = 0.f, bce = 0.f;
  #pragma unroll
  for (int k = 0; k < 4; ++k){
    float x = logits[k*NN + n];
    float yk = 1.0f / (1.0f + expf(-x));
    y += (sp[k] / tot) * yk;
    bce += lab * softplusf(-x) + (1.0f - lab) * softplusf(x);
  }
  out[1 + n] = y;
  __shared__ float pr[8];
  #pragma unroll
  for (int off = 1; off < 64; off <<= 1) bce += __shfl_xor(bce, off);
  if ((n & 63) == 0) pr[n >> 6] = bce;
  __syncthreads();
  if (n == 0){
    float ssum = 0.f;
    for (int i = 0; i < 8; ++i) ssum += pr[i];
    out[0] = ssum * (1.0f/512.0f);
  }
}

// ---------------- launcher ----------------
extern "C" void kernel_launch(void* const* d_in, const int* in_sizes, int n_in,
                              void* d_out, int out_size, void* d_ws, size_t ws_size,
                              hipStream_t stream) {
  const int*   node_tags = (const int*)  d_in[0];
  const float* adj       = (const float*)d_in[1];
  const int*   label     = (const int*)  d_in[2];
  const float* W_emb     = (const float*)d_in[3];
  const float* b_emb     = (const float*)d_in[4];
  const float* W_ih      = (const float*)d_in[5];
  const float* W_hh      = (const float*)d_in[6];
  const float* b_ih      = (const float*)d_in[7];
  const float* b_hh      = (const float*)d_in[8];
  const float* W1s       = (const float*)d_in[9];
  const float* b1s       = (const float*)d_in[10];
  const float* W2s       = (const float*)d_in[11];
  const float* b2s       = (const float*)d_in[12];
  const float* var_raw   = (const float*)d_in[13];
  float* out = (float*)d_out;

  float* ws     = (float*)d_ws;
  float* feat   = ws;                      // 512*128        = 65536
  float* IFW    = feat + 65536;            // 512*512        = 262144
  float* embed  = IFW + 262144;            // 512*128        = 65536
  float* logits = embed + 65536;           // 4*512          = 2048
  int*   orders = (int*)(logits + 2048);   // 512*512 int32  = 262144

  k_orders<<<dim3(NN),  dim3(64),  0, stream>>>(adj, orders);
  k_feat  <<<dim3(NN),  dim3(64),  0, stream>>>(node_tags, adj, W_emb, b_emb, feat);
  k_ifw   <<<dim3(NN),  dim3(256), 0, stream>>>(feat, W_ih, b_ih, b_hh, IFW);
  k_lstm  <<<dim3(32),  dim3(256), 0, stream>>>(W_hh, IFW, orders, embed);
  k_heads <<<dim3(NN),  dim3(128), 0, stream>>>(embed, W1s, b1s, W2s, b2s, logits);
  k_final <<<dim3(1),   dim3(512), 0, stream>>>(logits, label, var_raw, out);
}

// Round 3
// 1127.352 us; speedup vs baseline: 1.4567x; 1.3285x over previous
//
#include <hip/hip_runtime.h>
#include <hip/hip_bf16.h>
#include <stdint.h>

#define NN 512
#define EMBD 64
#define HID 128

typedef float f32x4 __attribute__((ext_vector_type(4)));
typedef short s16x8 __attribute__((ext_vector_type(8)));

// ---------------- Threefry-2x32 (exact JAX semantics) ----------------
__device__ __forceinline__ uint32_t rotl32(uint32_t v, int s){ return (v << s) | (v >> (32 - s)); }

__device__ __forceinline__ void tf2x32(uint32_t k0, uint32_t k1, uint32_t x0, uint32_t x1,
                                       uint32_t &o0, uint32_t &o1){
  uint32_t k2 = k0 ^ k1 ^ 0x1BD11BDAu;
  x0 += k0; x1 += k1;
  x0+=x1; x1=rotl32(x1,13); x1^=x0;
  x0+=x1; x1=rotl32(x1,15); x1^=x0;
  x0+=x1; x1=rotl32(x1,26); x1^=x0;
  x0+=x1; x1=rotl32(x1, 6); x1^=x0;
  x0 += k1; x1 += k2 + 1u;
  x0+=x1; x1=rotl32(x1,17); x1^=x0;
  x0+=x1; x1=rotl32(x1,29); x1^=x0;
  x0+=x1; x1=rotl32(x1,16); x1^=x0;
  x0+=x1; x1=rotl32(x1,24); x1^=x0;
  x0 += k2; x1 += k0 + 2u;
  x0+=x1; x1=rotl32(x1,13); x1^=x0;
  x0+=x1; x1=rotl32(x1,15); x1^=x0;
  x0+=x1; x1=rotl32(x1,26); x1^=x0;
  x0+=x1; x1=rotl32(x1, 6); x1^=x0;
  x0 += k0; x1 += k1 + 3u;
  x0+=x1; x1=rotl32(x1,17); x1^=x0;
  x0+=x1; x1=rotl32(x1,29); x1^=x0;
  x0+=x1; x1=rotl32(x1,16); x1^=x0;
  x0+=x1; x1=rotl32(x1,24); x1^=x0;
  x0 += k1; x1 += k2 + 4u;
  x0+=x1; x1=rotl32(x1,13); x1^=x0;
  x0+=x1; x1=rotl32(x1,15); x1^=x0;
  x0+=x1; x1=rotl32(x1,26); x1^=x0;
  x0+=x1; x1=rotl32(x1, 6); x1^=x0;
  x0 += k2; x1 += k0 + 5u;
  o0 = x0; o1 = x1;
}

// uniform(key,(n,),0.01,0.1) bit-exact elementwise transform
__device__ __forceinline__ float bits_to_noise(uint32_t bits){
  float u = __builtin_bit_cast(float, (bits >> 9) | 0x3f800000u) - 1.0f;
  const float dlt = 0.1f - 0.01f;
  float v = __fadd_rn(__fmul_rn(u, dlt), 0.01f); // no FMA, as XLA emits
  return fmaxf(0.01f, v);
}

__device__ __forceinline__ short f2bf(float f){
  uint32_t u = __builtin_bit_cast(uint32_t, f);
  u += 0x7fffu + ((u >> 16) & 1u);
  return (short)(u >> 16);
}

__device__ __forceinline__ float fsig(float x){
  return __builtin_amdgcn_rcpf(1.0f + __expf(-x));
}
__device__ __forceinline__ float ftanh(float x){
  float e = __expf(2.0f * x);
  return 1.0f - 2.0f * __builtin_amdgcn_rcpf(e + 1.0f);
}
__device__ __forceinline__ float softplusf(float x){
  return log1pf(expf(x));
}

// ---------------- fast 64-lane reductions (DPP + swizzle) ----------------
__device__ __forceinline__ float wave_fmax(float x){
  int xi;
  #define DSTEP(C) xi = __builtin_amdgcn_update_dpp(0, __builtin_bit_cast(int,x), C, 0xF, 0xF, true); \
                   x = fmaxf(x, __builtin_bit_cast(float,xi));
  DSTEP(0xB1)   /* xor1  quad_perm[1,0,3,2] */
  DSTEP(0x4E)   /* xor2  quad_perm[2,3,0,1] */
  DSTEP(0x141)  /* xor4  row_half_mirror    */
  DSTEP(0x140)  /* xor8  row_mirror         */
  #undef DSTEP
  xi = __builtin_amdgcn_ds_swizzle(__builtin_bit_cast(int,x), 0x401F); // xor16
  x = fmaxf(x, __builtin_bit_cast(float,xi));
  x = fmaxf(x, __shfl_xor(x, 32));
  return x;
}
__device__ __forceinline__ uint32_t wave_maxu(uint32_t x){
  int m;
  #define USTEP(C) m = __builtin_amdgcn_update_dpp(0, (int)x, C, 0xF, 0xF, true); \
                   x = x > (uint32_t)m ? x : (uint32_t)m;
  USTEP(0xB1) USTEP(0x4E) USTEP(0x141) USTEP(0x140)
  #undef USTEP
  m = __builtin_amdgcn_ds_swizzle((int)x, 0x401F);
  x = x > (uint32_t)m ? x : (uint32_t)m;
  uint32_t o = (uint32_t)__shfl_xor((int)x, 32);
  x = x > o ? x : o;
  return x;
}

// ---------------- mega-kernel body A: greedy noisy random-walk ----------------
// Winner of step t = argmax over unvisited i of adj[cur,i]+noise_i, noise in
// [0.01,0.1).  Candidates pruned to adj_i >= M-0.0901 (M = unvisited max).
// Integer key: adj multiple of 2^-23, noise multiple of 2^-30 (both exact f32
// power-2 scalings) -> key = (a23<<7)+n30 < 2^31.  Tie (equal key, different
// idx) resolved min-idx in a rare uniform branch.  Bit-identical to f64 path.
__device__ __forceinline__ void orders_body(const float* __restrict__ adj,
                                            int* __restrict__ orders, int s){
  int lane = threadIdx.x;
  __shared__ uint32_t kts[2*(NN-1)];
  __shared__ float ca[NN];
  __shared__ int   ci[NN];

  uint32_t ks0, ks1; tf2x32(0u, 42u, 0u, (uint32_t)s, ks0, ks1);
  for (int t = lane; t < NN-1; t += 64){
    uint32_t a, b; tf2x32(ks0, ks1, 0u, (uint32_t)t, a, b);
    kts[2*t] = a; kts[2*t+1] = b;
  }
  __syncthreads();

  uint32_t vis = 0;                       // bit e = visited(lane*8+e)
  if ((s >> 3) == lane) vis |= 1u << (s & 7);
  int cur = s;
  if (lane == 0) orders[(size_t)s*NN] = s;
  unsigned long long lt = (1ull << lane) - 1ull;

  for (int t = 0; t < NN-1; ++t){
    uint32_t kt0 = kts[2*t], kt1 = kts[2*t+1];
    const float4* r4 = (const float4*)(adj + (size_t)cur*NN);
    float4 v0 = r4[lane*2], v1 = r4[lane*2+1];
    float a[8] = {v0.x,v0.y,v0.z,v0.w,v1.x,v1.y,v1.z,v1.w};

    float mx = -1.f;
    #pragma unroll
    for (int e = 0; e < 8; ++e)
      mx = fmaxf(mx, ((vis >> e) & 1) ? -1.f : a[e]);
    mx = wave_fmax(mx);
    float T = mx - 0.0901f;

    // parallel ballots + prefix -> compact candidates
    int base = 0, pos[8]; uint32_t cm = 0;
    #pragma unroll
    for (int e = 0; e < 8; ++e){
      bool c = !((vis >> e) & 1) && (a[e] >= T);
      unsigned long long bal = __ballot(c);
      pos[e] = base + __popcll(bal & lt);
      base += __popcll(bal);
      if (c) cm |= 1u << e;
    }
    #pragma unroll
    for (int e = 0; e < 8; ++e)
      if ((cm >> e) & 1){ ca[pos[e]] = a[e]; ci[pos[e]] = lane*8 + e; }
    int total = base;

    // evaluate candidates (threefry only here); same-wave LDS RAW is ordered
    uint32_t bk = 0; int bi = 0x7fffffff;
    for (int b0 = 0; b0 < total; b0 += 64){
      int k = b0 + lane;
      if (k < total){
        int idx = ci[k]; float av = ca[k];
        uint32_t x0, x1;
        tf2x32(kt0, kt1, 0u, (uint32_t)idx, x0, x1);
        float nz = bits_to_noise(x0 ^ x1);
        uint32_t a23 = (uint32_t)(av * 8388608.0f);      // *2^23 exact
        uint32_t n30 = (uint32_t)(nz * 1073741824.0f);   // *2^30 exact
        uint32_t key = (a23 << 7) + n30;
        if (key > bk || (key == bk && idx < bi)){ bk = key; bi = idx; }
      }
    }
    uint32_t km = wave_maxu(bk);
    unsigned long long msk = __ballot(bk == km);
    int widx;
    if (__popcll(msk) == 1){
      widx = __shfl(bi, __ffsll((long long)msk) - 1);
    } else {                                // rare exact-tie path
      int iv = (bk == km) ? bi : 0x7fffffff;
      #pragma unroll
      for (int off = 1; off < 64; off <<= 1){
        int o = __shfl_xor(iv, off);
        iv = o < iv ? o : iv;
      }
      widx = iv;
    }
    cur = widx;
    if ((widx >> 3) == lane) vis |= 1u << (widx & 7);
    if (lane == 0) orders[(size_t)s*NN + t + 1] = widx;
  }
}

// ---------------- mega-kernel body B: fused input_feat + IFW ----------------
__device__ __forceinline__ void featifw_body(int n, const int* __restrict__ tags,
    const float* __restrict__ adj, const float* __restrict__ W_emb,
    const float* __restrict__ b_emb, const float* __restrict__ W_ih,
    const float* __restrict__ b_ih, const float* __restrict__ b_hh,
    float* __restrict__ IFW){
  int tid = threadIdx.x;                 // = embedding dim d (0..63)
  __shared__ int tg[NN];
  __shared__ __align__(16) float xs[2*EMBD];
  for (int i = tid; i < NN; i += 64) tg[i] = tags[i];
  float nf = W_emb[tg[n]*EMBD + tid] + b_emb[tid];
  float ac = 0.f;
  for (int m = 0; m < NN; ++m){
    if (adj[(size_t)n*NN + m] > 0.5f) ac += W_emb[tg[m]*EMBD + tid];
  }
  xs[tid]        = nf;
  xs[EMBD + tid] = ac + b_emb[tid];
  __syncthreads();
  const float4* xs4 = (const float4*)xs;
  for (int it = 0; it < 8; ++it){
    int g = it*64 + tid;
    const float4* wr4 = (const float4*)(W_ih + (size_t)g*(2*EMBD));
    float acc = b_ih[g] + b_hh[g];
    #pragma unroll 8
    for (int kk = 0; kk < 32; ++kk){
      float4 wv = wr4[kk], xv = xs4[kk];
      acc += wv.x*xv.x + wv.y*xv.y + wv.z*xv.z + wv.w*xv.w;
    }
    IFW[(size_t)n*(4*HID) + g] = acc;
  }
}

__global__ __launch_bounds__(64) void k_mega1(const float* __restrict__ adj,
    int* __restrict__ orders, const int* __restrict__ tags,
    const float* __restrict__ W_emb, const float* __restrict__ b_emb,
    const float* __restrict__ W_ih, const float* __restrict__ b_ih,
    const float* __restrict__ b_hh, float* __restrict__ IFW){
  if (blockIdx.x < NN) orders_body(adj, orders, blockIdx.x);
  else                 featifw_body(blockIdx.x - NN, tags, adj, W_emb, b_emb,
                                    W_ih, b_ih, b_hh, IFW);
}

// ---------------- K2: persistent LSTM (8 waves) + fused MLP heads ----------------
__device__ __forceinline__ void lstm_step(int t, int w, int l15, int l4,
    const short (*hread)[HID+8], short (*hwrite)[HID+8],
    float (&vIFc)[4][4], float (&vIFn)[4][4],
    const s16x8 (&Bf)[4][4], float (&c)[4], float (&emb)[4],
    const int* ord_s, const float* __restrict__ IFW){
  // prefetch next step's IFW gather (lands during this step's MFMA+epilogue)
  int tn = (t + 1 < NN) ? t + 1 : NN - 1;
  #pragma unroll
  for (int r = 0; r < 4; ++r){
    int ord = ord_s[(l4*4 + r)*NN + tn];
    const float* base = IFW + (size_t)ord*(4*HID) + w*16 + l15;
    #pragma unroll
    for (int q = 0; q < 4; ++q) vIFn[q][r] = base[q*HID];
  }
  s16x8 Af[4];
  #pragma unroll
  for (int kt = 0; kt < 4; ++kt)
    Af[kt] = *(const s16x8*)&hread[l15][kt*32 + l4*8];
  f32x4 acc[4];
  #pragma unroll
  for (int q = 0; q < 4; ++q){
    f32x4 a = {vIFc[q][0], vIFc[q][1], vIFc[q][2], vIFc[q][3]}; // C-init = x@W_ih + b
    #pragma unroll
    for (int kt = 0; kt < 4; ++kt)
      a = __builtin_amdgcn_mfma_f32_16x16x32_bf16(Af[kt], Bf[q][kt], a, 0, 0, 0);
    acc[q] = a;
  }
  int col = w*16 + l15;
  #pragma unroll
  for (int r = 0; r < 4; ++r){
    float si = fsig(acc[0][r]);
    float sf = fsig(acc[1][r]);
    float tg = ftanh(acc[2][r]);
    float so = fsig(acc[3][r]);
    float cn = sf * c[r] + si * tg;
    c[r] = cn;
    float h = so * ftanh(cn);
    emb[r] += h;
    hwrite[l4*4 + r][col] = f2bf(h);
  }
  __syncthreads();
}

__global__ __launch_bounds__(512, 2) void k_lstm(const float* __restrict__ W_hh,
    const float* __restrict__ IFW, const int* __restrict__ orders,
    const float* __restrict__ W1s, const float* __restrict__ b1s,
    const float* __restrict__ W2s, const float* __restrict__ b2s,
    float* __restrict__ logits){
  int wg = blockIdx.x, tid = threadIdx.x;
  int w = tid >> 6, l = tid & 63, l15 = l & 15, l4 = l >> 4;
  __shared__ int ord_s[16*NN];                        // 32 KB
  __shared__ __align__(16) short hbuf[2][16][HID+8];  // 8.7 KB (both buffers)
  __shared__ float part[4][2];

  for (int i = tid; i < 16*NN; i += 512){
    int m = i >> 9, t = i & (NN-1);
    ord_s[i] = orders[(size_t)(16*wg + m)*NN + t];
  }
  for (int i = tid; i < 16*(HID+8); i += 512)
    ((short*)hbuf[0])[i] = 0;

  // W_hh -> bf16 B-fragments in registers; wave w owns dim-tile w (16 dims)
  s16x8 Bf[4][4];
  #pragma unroll
  for (int q = 0; q < 4; ++q)
    #pragma unroll
    for (int kt = 0; kt < 4; ++kt){
      int g = q*HID + w*16 + l15;
      const float* src = W_hh + (size_t)g*HID + kt*32 + l4*8;
      s16x8 v;
      #pragma unroll
      for (int e = 0; e < 8; ++e) v[e] = f2bf(src[e]);
      Bf[q][kt] = v;
    }
  __syncthreads();

  float c[4] = {0,0,0,0}, emb[4] = {0,0,0,0};
  float vA[4][4], vB[4][4];
  #pragma unroll
  for (int r = 0; r < 4; ++r){
    int ord = ord_s[(l4*4 + r)*NN];
    const float* base = IFW + (size_t)ord*(4*HID) + w*16 + l15;
    #pragma unroll
    for (int q = 0; q < 4; ++q) vA[q][r] = base[q*HID];
  }

  for (int t2 = 0; t2 < NN/2; ++t2){
    lstm_step(2*t2,     w, l15, l4, hbuf[0], hbuf[1], vA, vB, Bf, c, emb, ord_s, IFW);
    lstm_step(2*t2 + 1, w, l15, l4, hbuf[1], hbuf[0], vB, vA, Bf, c, emb, ord_s, IFW);
  }

  // ---- fused MLP heads over this block's 16 nodes ----
  float* eL = (float*)&hbuf[0][0][0];     // 8 KB reuse (<= 8.7 KB)
  #pragma unroll
  for (int r = 0; r < 4; ++r)
    eL[(l4*4 + r)*HID + w*16 + l15] = emb[r] * (1.0f/512.0f);
  __syncthreads();

  int hk = tid >> 7;          // head 0..3
  int u  = tid & 127;         // hidden unit
  float b1v = b1s[hk*HID + u];
  float w2v = W2s[hk*HID + u];
  const float* wcol = W1s + (size_t)hk*HID*HID + u;
  for (int m = 0; m < 16; ++m){
    const float4* es4 = (const float4*)(eL + m*HID);
    float pre = b1v;
    #pragma unroll 4
    for (int d4 = 0; d4 < 32; ++d4){
      float4 e4 = es4[d4];
      pre += e4.x * wcol[(4*d4+0)*HID];
      pre += e4.y * wcol[(4*d4+1)*HID];
      pre += e4.z * wcol[(4*d4+2)*HID];
      pre += e4.w * wcol[(4*d4+3)*HID];
    }
    float v = fmaxf(pre, 0.f) * w2v;
    #pragma unroll
    for (int off = 1; off < 64; off <<= 1) v += __shfl_xor(v, off);
    if (l == 0) part[hk][(tid >> 6) & 1] = v;
    __syncthreads();
    if (tid < 4) logits[tid*NN + 16*wg + m] = part[tid][0] + part[tid][1] + b2s[tid];
    __syncthreads();
  }
}

// ---------------- K3: BCE loss + softplus-weighted mixture ----------------
__global__ __launch_bounds__(512) void k_final(const float* __restrict__ logits,
                                               const int* __restrict__ label,
                                               const float* __restrict__ var_raw,
                                               float* __restrict__ out){
  int n = threadIdx.x;
  float lab = (float)label[0];
  float sp[4]; float tot = 0.f;
  #pragma unroll
  for (int k = 0; k < 4; ++k){ sp[k] = softplusf(var_raw[k]); tot += sp[k]; }
  float y = 0.f, bce = 0.f;
  #pragma unroll
  for (int k = 0; k < 4; ++k){
    float x = logits[k*NN + n];
    float yk = 1.0f / (1.0f + expf(-x));
    y += (sp[k] / tot) * yk;
    bce += lab * softplusf(-x) + (1.0f - lab) * softplusf(x);
  }
  out[1 + n] = y;
  __shared__ float pr[8];
  #pragma unroll
  for (int off = 1; off < 64; off <<= 1) bce += __shfl_xor(bce, off);
  if ((n & 63) == 0) pr[n >> 6] = bce;
  __syncthreads();
  if (n == 0){
    float ssum = 0.f;
    for (int i = 0; i < 8; ++i) ssum += pr[i];
    out[0] = ssum * (1.0f/512.0f);
  }
}

// ---------------- launcher ----------------
extern "C" void kernel_launch(void* const* d_in, const int* in_sizes, int n_in,
                              void* d_out, int out_size, void* d_ws, size_t ws_size,
                              hipStream_t stream) {
  const int*   node_tags = (const int*)  d_in[0];
  const float* adj       = (const float*)d_in[1];
  const int*   label     = (const int*)  d_in[2];
  const float* W_emb     = (const float*)d_in[3];
  const float* b_emb     = (const float*)d_in[4];
  const float* W_ih      = (const float*)d_in[5];
  const float* W_hh      = (const float*)d_in[6];
  const float* b_ih      = (const float*)d_in[7];
  const float* b_hh      = (const float*)d_in[8];
  const float* W1s       = (const float*)d_in[9];
  const float* b1s       = (const float*)d_in[10];
  const float* W2s       = (const float*)d_in[11];
  const float* b2s       = (const float*)d_in[12];
  const float* var_raw   = (const float*)d_in[13];
  float* out = (float*)d_out;

  float* ws     = (float*)d_ws;
  float* IFW    = ws + 65536;              // 512*512
  float* logits = IFW + 262144 + 65536;    // 4*512 (embed slot unused)
  int*   orders = (int*)(logits + 2048);   // 512*512 int32

  k_mega1<<<dim3(2*NN), dim3(64),  0, stream>>>(adj, orders, node_tags, W_emb,
                                                b_emb, W_ih, b_ih, b_hh, IFW);
  k_lstm <<<dim3(32),   dim3(512), 0, stream>>>(W_hh, IFW, orders, W1s, b1s,
                                                W2s, b2s, logits);
  k_final<<<dim3(1),    dim3(512), 0, stream>>>(logits, label, var_raw, out);
}